// Round 2
// baseline (302.237 us; speedup 1.0000x reference)
//
#include <hip/hip_runtime.h>

typedef __attribute__((ext_vector_type(8))) short short8;
typedef __attribute__((ext_vector_type(4))) float f32x4;
typedef __attribute__((ext_vector_type(4))) float float4v;
typedef __attribute__((ext_vector_type(8))) float f32x8;
typedef __attribute__((ext_vector_type(4))) unsigned short us4;
typedef __attribute__((ext_vector_type(4))) unsigned int uint4v;

#define DEVI __device__ __forceinline__
#define MFMA16(a,b,c) __builtin_amdgcn_mfma_f32_16x16x32_bf16((a),(b),(c),0,0,0)

// ---------- helpers ----------
DEVI unsigned short f2bf(float x) {            // f32 -> bf16 bits, RNE
    unsigned u = __builtin_bit_cast(unsigned, x);
    u += 0x7FFFu + ((u >> 16) & 1u);
    return (unsigned short)(u >> 16);
}
DEVI float bf2f(unsigned short b) {
    return __builtin_bit_cast(float, ((unsigned)b) << 16);
}

// ---------- prep: split hidden f32 -> bf16 hi/lo ----------
__global__ __launch_bounds__(256) void k_prep_hidden(const float* __restrict__ hid,
                                                     unsigned short* __restrict__ hh,
                                                     unsigned short* __restrict__ hl) {
    int i = blockIdx.x * 256 + threadIdx.x;     // 524288 threads, 4 f32 each
    float4v v = *reinterpret_cast<const float4v*>(hid + (long)i * 4);
    us4 a, b;
    #pragma unroll
    for (int j = 0; j < 4; ++j) {
        float x = v[j];
        unsigned short h = f2bf(x);
        a[j] = h;
        b[j] = f2bf(x - bf2f(h));
    }
    *reinterpret_cast<us4*>(hh + (long)i * 4) = a;
    *reinterpret_cast<us4*>(hl + (long)i * 4) = b;
}

// ---------- prep: transpose weights, split Wq/Wk ----------
__global__ __launch_bounds__(256) void k_prep_w(const float* __restrict__ wq, const float* __restrict__ wk,
                                                const float* __restrict__ wv, const float* __restrict__ wo,
                                                unsigned short* wqthi, unsigned short* wqtlo,
                                                unsigned short* wkthi, unsigned short* wktlo,
                                                unsigned short* wvt, unsigned short* wot) {
    int t = blockIdx.x * 256 + threadIdx.x;     // 4*262144 threads
    int which = t >> 18;
    int idx = t & 0x3FFFF;
    int k = idx >> 9, n = idx & 511;
    int o = n * 512 + k;                        // transposed [n][k]
    if (which == 0) {
        float x = wq[idx]; unsigned short h = f2bf(x);
        wqthi[o] = h; wqtlo[o] = f2bf(x - bf2f(h));
    } else if (which == 1) {
        float x = wk[idx]; unsigned short h = f2bf(x);
        wkthi[o] = h; wktlo[o] = f2bf(x - bf2f(h));
    } else if (which == 2) {
        wvt[o] = f2bf(wv[idx]);
    } else {
        wot[o] = f2bf(wo[idx]);
    }
}

// ---------- prep: bias table biasT[h][rel+2047] ----------
DEVI int bucket_large(int a) {   // exact integer thresholds of 8+floor(2*log2(a/8)), clamp 15
    if (a < 12) return 8;
    if (a < 16) return 9;
    if (a < 23) return 10;
    if (a < 32) return 11;
    if (a < 46) return 12;
    if (a < 64) return 13;
    if (a < 91) return 14;
    return 15;
}
__global__ __launch_bounds__(256) void k_prep_bias(const float* __restrict__ emb, float* __restrict__ biasT) {
    int t = blockIdx.x * 256 + threadIdx.x;
    if (t >= 8 * 4095) return;
    int h = t / 4095;
    int idx = t - h * 4095;
    int rel = idx - 2047;                // rel = k - q
    int a = rel < 0 ? -rel : rel;
    int bucket = (rel > 0 ? 16 : 0) + (a < 8 ? a : bucket_large(a));
    biasT[h * 4096 + idx] = emb[bucket * 8 + h];
}

// ---------- fused QKV projection: hidden[4096x512] @ {Wq,Wk,Wv} ----------
// Q/K: split bf16 (3 MFMAs), outputs hi/lo bf16 at [row][h*64+d].
// V: plain bf16, output transposed vT[b][h][d][s].
__global__ __launch_bounds__(256) void k_proj(const unsigned short* __restrict__ hh,
                                              const unsigned short* __restrict__ hl,
                                              const unsigned short* __restrict__ wqthi, const unsigned short* __restrict__ wqtlo,
                                              const unsigned short* __restrict__ wkthi, const unsigned short* __restrict__ wktlo,
                                              const unsigned short* __restrict__ wvt,
                                              unsigned short* __restrict__ q_hi, unsigned short* __restrict__ q_lo,
                                              unsigned short* __restrict__ k_hi, unsigned short* __restrict__ k_lo,
                                              unsigned short* __restrict__ vT) {
    const int wgid = blockIdx.x;            // 384 = 32 mt * 12 nt
    const int nt = wgid % 12, mt = wgid / 12;
    const int sec = nt >> 2;                // 0:Q 1:K 2:V
    const bool isv = (sec == 2);
    const int tid = threadIdx.x, wv = tid >> 6, lane = tid & 63;
    const int wr = wv >> 1, wc = wv & 1;
    const int g = lane >> 4, li = lane & 15;
    const int m0 = mt * 128 + wr * 64;
    const int n0 = (nt & 3) * 128 + wc * 64;    // col within section [0,512)
    const unsigned short* bh_ = (sec == 0) ? wqthi : (sec == 1) ? wkthi : wvt;
    const unsigned short* bl_ = (sec == 0) ? wqtlo : wktlo;

    f32x4 zf = {0.f, 0.f, 0.f, 0.f};
    f32x4 acc[4][4];
    #pragma unroll
    for (int i = 0; i < 4; ++i)
        #pragma unroll
        for (int j = 0; j < 4; ++j) acc[i][j] = zf;

    for (int ks = 0; ks < 512; ks += 32) {
        int koff = ks + g * 8;
        short8 ah[4], al[4], bhf[4], blf[4];
        #pragma unroll
        for (int i = 0; i < 4; ++i) {
            long ar = (long)(m0 + i * 16 + li) * 512 + koff;
            ah[i] = *reinterpret_cast<const short8*>(hh + ar);
            if (!isv) al[i] = *reinterpret_cast<const short8*>(hl + ar);
            long br = (long)(n0 + i * 16 + li) * 512 + koff;
            bhf[i] = *reinterpret_cast<const short8*>(bh_ + br);
            if (!isv) blf[i] = *reinterpret_cast<const short8*>(bl_ + br);
        }
        #pragma unroll
        for (int i = 0; i < 4; ++i)
            #pragma unroll
            for (int j = 0; j < 4; ++j) {
                acc[i][j] = MFMA16(ah[i], bhf[j], acc[i][j]);
                if (!isv) {
                    acc[i][j] = MFMA16(ah[i], blf[j], acc[i][j]);
                    acc[i][j] = MFMA16(al[i], bhf[j], acc[i][j]);
                }
            }
    }

    if (!isv) {
        unsigned short* ohi = (sec == 0) ? q_hi : k_hi;
        unsigned short* olo = (sec == 0) ? q_lo : k_lo;
        #pragma unroll
        for (int i = 0; i < 4; ++i) {
            int rowb = m0 + i * 16 + g * 4;
            #pragma unroll
            for (int j = 0; j < 4; ++j) {
                int col = n0 + j * 16 + li;
                #pragma unroll
                for (int r = 0; r < 4; ++r) {
                    float x = acc[i][j][r];
                    unsigned short hb = f2bf(x);
                    long o = (long)(rowb + r) * 512 + col;
                    ohi[o] = hb;
                    olo[o] = f2bf(x - bf2f(hb));
                }
            }
        }
    } else {
        #pragma unroll
        for (int i = 0; i < 4; ++i) {
            int rowb = m0 + i * 16 + g * 4;      // 4 consecutive s
            int bb = rowb >> 11, ss = rowb & 2047;
            #pragma unroll
            for (int j = 0; j < 4; ++j) {
                int nv = n0 + j * 16 + li;       // [0,512)
                int hh2 = nv >> 6, dd = nv & 63;
                us4 w;
                #pragma unroll
                for (int r = 0; r < 4; ++r) w[r] = f2bf(acc[i][j][r]);
                *reinterpret_cast<us4*>(vT + ((long)((bb * 8 + hh2) * 64 + dd)) * 2048 + ss) = w;
            }
        }
    }
}

// ---------- flash attention ----------
// grid 512: wg = bh*32 + qb ; 4 waves, each owns 16 q-rows.
// Swapped QK^T: D = K_tile(16k x 32d) * Q^T(32d x 16q) -> lane holds scores for q=lane&15.
__global__ __launch_bounds__(256) void k_attn(const unsigned short* __restrict__ qhi,
                                              const unsigned short* __restrict__ qlo,
                                              const unsigned short* __restrict__ khi,
                                              const unsigned short* __restrict__ klo,
                                              const unsigned short* __restrict__ vT,
                                              const float* __restrict__ biasT,
                                              unsigned short* __restrict__ ctx) {
    __shared__ float lbias[4095];
    const int wg = blockIdx.x;
    const int bh = wg >> 5, qb = wg & 31;
    const int b = bh >> 3, h = bh & 7;
    const int tid = threadIdx.x;
    const int wv = tid >> 6, lane = tid & 63;
    const int g = lane >> 4, qi = lane & 15;

    for (int i = tid; i < 4095; i += 256) lbias[i] = biasT[h * 4096 + i];
    __syncthreads();

    const int q = qb * 64 + wv * 16 + qi;                 // this lane's q row
    const long rowQ = (long)(b * 2048 + q) * 512 + h * 64;
    short8 qh[2], ql[2];
    #pragma unroll
    for (int dc = 0; dc < 2; ++dc) {
        int off = dc * 32 + g * 8;
        qh[dc] = *reinterpret_cast<const short8*>(qhi + rowQ + off);
        ql[dc] = *reinterpret_cast<const short8*>(qlo + rowQ + off);
    }
    const long kbase = (long)(b * 2048) * 512 + h * 64;
    const long vbase = (long)((b * 8 + h) * 64) * 2048;

    f32x4 zf = {0.f, 0.f, 0.f, 0.f};
    f32x4 oacc[4] = {zf, zf, zf, zf};
    float m_run = -__builtin_inff(), l_run = 0.f;

    for (int k0 = 0; k0 < 2048; k0 += 32) {
        short8 akh[2][2], akl[2][2];
        #pragma unroll
        for (int t2 = 0; t2 < 2; ++t2)
            #pragma unroll
            for (int dc = 0; dc < 2; ++dc) {
                long a = kbase + (long)(k0 + t2 * 16 + qi) * 512 + dc * 32 + g * 8;
                akh[t2][dc] = *reinterpret_cast<const short8*>(khi + a);
                akl[t2][dc] = *reinterpret_cast<const short8*>(klo + a);
            }
        f32x4 st[2] = {zf, zf};
        #pragma unroll
        for (int t2 = 0; t2 < 2; ++t2)
            #pragma unroll
            for (int dc = 0; dc < 2; ++dc) {
                st[t2] = MFMA16(akh[t2][dc], qh[dc], st[t2]);
                st[t2] = MFMA16(akh[t2][dc], ql[dc], st[t2]);
                st[t2] = MFMA16(akl[t2][dc], qh[dc], st[t2]);
            }
        // bias + online softmax (scores for this lane: k = k0 + 16*t2 + 4*g + r)
        float s8[8];
        #pragma unroll
        for (int t2 = 0; t2 < 2; ++t2)
            #pragma unroll
            for (int r = 0; r < 4; ++r) {
                int kk = k0 + t2 * 16 + g * 4 + r;
                s8[t2 * 4 + r] = st[t2][r] + lbias[kk - q + 2047];
            }
        float mx = s8[0];
        #pragma unroll
        for (int i = 1; i < 8; ++i) mx = fmaxf(mx, s8[i]);
        mx = fmaxf(mx, __shfl_xor(mx, 16));
        mx = fmaxf(mx, __shfl_xor(mx, 32));
        float mnew = fmaxf(m_run, mx);
        float scale = __expf(m_run - mnew);
        float psum = 0.f;
        unsigned pu[4];
        #pragma unroll
        for (int t2 = 0; t2 < 2; ++t2) {
            float p0 = __expf(s8[t2 * 4 + 0] - mnew);
            float p1 = __expf(s8[t2 * 4 + 1] - mnew);
            float p2 = __expf(s8[t2 * 4 + 2] - mnew);
            float p3 = __expf(s8[t2 * 4 + 3] - mnew);
            unsigned short b0 = f2bf(p0), b1 = f2bf(p1), b2 = f2bf(p2), b3v = f2bf(p3);
            // denominator from the SAME rounded weights PV will use
            psum += bf2f(b0) + bf2f(b1) + bf2f(b2) + bf2f(b3v);
            pu[t2 * 2 + 0] = (unsigned)b0 | ((unsigned)b1 << 16);
            pu[t2 * 2 + 1] = (unsigned)b2 | ((unsigned)b3v << 16);
        }
        l_run = l_run * scale + psum;
        m_run = mnew;
        #pragma unroll
        for (int dt = 0; dt < 4; ++dt) {
            oacc[dt][0] *= scale; oacc[dt][1] *= scale;
            oacc[dt][2] *= scale; oacc[dt][3] *= scale;
        }
        // exchange p -> PV B-fragment: target group g needs k in [8g, 8g+8)
        uint4v pf;
        const int t_sel = g >> 1, b3 = g & 1;
        #pragma unroll
        for (int c = 0; c < 4; ++c) {
            int gp = 2 * b3 + (c >> 1);
            int srcLane = qi | (gp << 4);
            unsigned y0 = __shfl(pu[c & 1], srcLane);
            unsigned y1 = __shfl(pu[2 + (c & 1)], srcLane);
            pf[c] = t_sel ? y1 : y0;
        }
        short8 pfrag = __builtin_bit_cast(short8, pf);
        // PV: oaccT[d][q] += V^T(16d x 32k) * P^T(32k x 16q)
        #pragma unroll
        for (int dt = 0; dt < 4; ++dt) {
            short8 vf = *reinterpret_cast<const short8*>(
                vT + vbase + (long)(dt * 16 + qi) * 2048 + k0 + g * 8);
            oacc[dt] = MFMA16(vf, pfrag, oacc[dt]);
        }
    }
    float lt = l_run;
    lt += __shfl_xor(lt, 16);
    lt += __shfl_xor(lt, 32);
    float inv = 1.0f / lt;
    const long crow = (long)(b * 2048 + q) * 512 + h * 64;   // col of D = qi = this lane's q
    #pragma unroll
    for (int dt = 0; dt < 4; ++dt) {
        us4 w;
        #pragma unroll
        for (int r = 0; r < 4; ++r) w[r] = f2bf(oacc[dt][r] * inv);
        *reinterpret_cast<us4*>(ctx + crow + dt * 16 + g * 4) = w;
    }
}

// ---------- output projection: ctx[4096x512] @ Wo -> d_out (f32) ----------
__global__ __launch_bounds__(256) void k_oproj(const unsigned short* __restrict__ ctx,
                                               const unsigned short* __restrict__ wot,
                                               float* __restrict__ outp) {
    const int wgid = blockIdx.x;            // 128 = 32 mt * 4 nt
    const int nt = wgid & 3, mt = wgid >> 2;
    const int tid = threadIdx.x, wv = tid >> 6, lane = tid & 63;
    const int wr = wv >> 1, wc = wv & 1;
    const int g = lane >> 4, li = lane & 15;
    const int m0 = mt * 128 + wr * 64;
    const int n0 = nt * 128 + wc * 64;

    f32x4 zf = {0.f, 0.f, 0.f, 0.f};
    f32x4 acc[4][4];
    #pragma unroll
    for (int i = 0; i < 4; ++i)
        #pragma unroll
        for (int j = 0; j < 4; ++j) acc[i][j] = zf;

    for (int ks = 0; ks < 512; ks += 32) {
        int koff = ks + g * 8;
        short8 af[4], bf[4];
        #pragma unroll
        for (int i = 0; i < 4; ++i) {
            af[i] = *reinterpret_cast<const short8*>(ctx + (long)(m0 + i * 16 + li) * 512 + koff);
            bf[i] = *reinterpret_cast<const short8*>(wot + (long)(n0 + i * 16 + li) * 512 + koff);
        }
        #pragma unroll
        for (int i = 0; i < 4; ++i)
            #pragma unroll
            for (int j = 0; j < 4; ++j)
                acc[i][j] = MFMA16(af[i], bf[j], acc[i][j]);
    }
    #pragma unroll
    for (int i = 0; i < 4; ++i) {
        int rowb = m0 + i * 16 + g * 4;
        #pragma unroll
        for (int j = 0; j < 4; ++j) {
            int col = n0 + j * 16 + li;
            #pragma unroll
            for (int r = 0; r < 4; ++r)
                outp[(long)(rowb + r) * 512 + col] = acc[i][j][r];
        }
    }
}

// ---------- position_bias writer: [8][2048][2048] f32 ----------
__global__ __launch_bounds__(256) void k_biasout(const float* __restrict__ biasT,
                                                 float* __restrict__ outb) {
    long t = (long)blockIdx.x * 256 + threadIdx.x;   // 4,194,304 threads, 8 elems each
    int h = (int)(t >> 19);
    long r = t & 524287;
    int qq = (int)(r >> 8);
    int k8 = (int)(r & 255) * 8;
    const float* src = biasT + h * 4096 + (k8 - qq + 2047);
    f32x8 w;
    #pragma unroll
    for (int i = 0; i < 8; ++i) w[i] = src[i];
    *reinterpret_cast<f32x8*>(outb + t * 8) = w;
}

// ---------- launch ----------
extern "C" void kernel_launch(void* const* d_in, const int* in_sizes, int n_in,
                              void* d_out, int out_size, void* d_ws, size_t ws_size,
                              hipStream_t stream) {
    const float* hidden = (const float*)d_in[0];
    const float* Wq = (const float*)d_in[1];
    const float* Wk = (const float*)d_in[2];
    const float* Wv = (const float*)d_in[3];
    const float* Wo = (const float*)d_in[4];
    const float* emb = (const float*)d_in[5];
    float* out = (float*)d_out;

    char* ws = (char*)d_ws;
    size_t off = 0;
    auto alloc = [&](size_t bytes) { char* p = ws + off; off += (bytes + 255) & ~(size_t)255; return p; };

    unsigned short* hid_hi = (unsigned short*)alloc(4096ull * 512 * 2);
    unsigned short* hid_lo = (unsigned short*)alloc(4096ull * 512 * 2);
    unsigned short* wqthi  = (unsigned short*)alloc(512ull * 512 * 2);
    unsigned short* wqtlo  = (unsigned short*)alloc(512ull * 512 * 2);
    unsigned short* wkthi  = (unsigned short*)alloc(512ull * 512 * 2);
    unsigned short* wktlo  = (unsigned short*)alloc(512ull * 512 * 2);
    unsigned short* wvt    = (unsigned short*)alloc(512ull * 512 * 2);
    unsigned short* wot    = (unsigned short*)alloc(512ull * 512 * 2);
    float*          biasT  = (float*)alloc(8ull * 4096 * 4);
    unsigned short* q_hi   = (unsigned short*)alloc(4096ull * 512 * 2);
    unsigned short* q_lo   = (unsigned short*)alloc(4096ull * 512 * 2);
    unsigned short* k_hi   = (unsigned short*)alloc(4096ull * 512 * 2);
    unsigned short* k_lo   = (unsigned short*)alloc(4096ull * 512 * 2);
    unsigned short* vT     = (unsigned short*)alloc(4096ull * 512 * 2);
    unsigned short* ctx    = (unsigned short*)alloc(4096ull * 512 * 2);

    k_prep_hidden<<<2048, 256, 0, stream>>>(hidden, hid_hi, hid_lo);
    k_prep_w<<<4096, 256, 0, stream>>>(Wq, Wk, Wv, Wo, wqthi, wqtlo, wkthi, wktlo, wvt, wot);
    k_prep_bias<<<128, 256, 0, stream>>>(emb, biasT);
    k_proj<<<384, 256, 0, stream>>>(hid_hi, hid_lo, wqthi, wqtlo, wkthi, wktlo, wvt,
                                    q_hi, q_lo, k_hi, k_lo, vT);
    k_attn<<<512, 256, 0, stream>>>(q_hi, q_lo, k_hi, k_lo, vT, biasT, ctx);
    k_oproj<<<128, 256, 0, stream>>>(ctx, wot, out);
    k_biasout<<<16384, 256, 0, stream>>>(biasT, out + 2097152);
}